// Round 5
// baseline (415.801 us; speedup 1.0000x reference)
//
#include <hip/hip_runtime.h>

// Problem dims
#define S_ 32
#define T_ 64
#define B_ 64
#define V_ 32000
#define E_ 128
#define H_ 128
#define G_ 128
#define C_ 5

typedef short s8v __attribute__((ext_vector_type(8)));   // 8 bf16 payload
typedef __bf16 b8v __attribute__((ext_vector_type(8)));
typedef float f32x4 __attribute__((ext_vector_type(4)));

// --- MFMA wrapper: tolerate either builtin operand signature (short8 or bf16x8)
template <typename V>
__device__ inline auto mfma_sel(V a, V b, f32x4 c, int)
    -> decltype(__builtin_amdgcn_mfma_f32_16x16x32_bf16(a, b, c, 0, 0, 0)) {
  return __builtin_amdgcn_mfma_f32_16x16x32_bf16(a, b, c, 0, 0, 0);
}
template <typename V>
__device__ inline f32x4 mfma_sel(V a, V b, f32x4 c, long) {
  return __builtin_amdgcn_mfma_f32_16x16x32_bf16(
      __builtin_bit_cast(b8v, a), __builtin_bit_cast(b8v, b), c, 0, 0, 0);
}
__device__ inline f32x4 mfma16(s8v a, s8v b, f32x4 c) { return mfma_sel(a, b, c, 0); }

__device__ inline float b2f(unsigned short u) {
  union { unsigned int i; float f; } v; v.i = ((unsigned int)u) << 16; return v.f;
}
// round-to-nearest (ties away) — 2 instr
__device__ inline unsigned short f2b(float f) {
  union { float f; unsigned int i; } v; v.f = f;
  return (unsigned short)((v.i + 0x8000u) >> 16);
}
// full-RNE for precomputed tables
__device__ inline unsigned short f2b_rne(float f) {
  union { float f; unsigned int i; } v; v.f = f;
  unsigned int r = (v.i + 0x7fffu + ((v.i >> 16) & 1u)) >> 16;
  return (unsigned short)r;
}
__device__ inline s8v cvt8(const float* p) {
  const float4 a = *(const float4*)p;
  const float4 b = *(const float4*)(p + 4);
  s8v r;
  r[0] = (short)f2b_rne(a.x); r[1] = (short)f2b_rne(a.y);
  r[2] = (short)f2b_rne(a.z); r[3] = (short)f2b_rne(a.w);
  r[4] = (short)f2b_rne(b.x); r[5] = (short)f2b_rne(b.y);
  r[6] = (short)f2b_rne(b.z); r[7] = (short)f2b_rne(b.w);
  return r;
}
// division-free activations (v_rcp_f32 + v_exp_f32; exact saturation at +-inf)
__device__ inline float fsigm(float x) {
  return __builtin_amdgcn_rcpf(1.f + __builtin_amdgcn_exp2f(-1.44269504f * x));
}
__device__ inline float ftanh(float x) {
  return 1.f - 2.f * __builtin_amdgcn_rcpf(1.f + __builtin_amdgcn_exp2f(2.88539008f * x));
}
// LDS-only barrier: global loads stay in flight across it
__device__ inline void lds_barrier() {
  asm volatile("s_waitcnt lgkmcnt(0)\n\ts_barrier" ::: "memory");
}

// ============================================================================
// K1: gtab = emb @ Wih_intra^T + bih (+bhh r,z folded). MFMA GEMM.
// Blocks 3000-3003: transpose W_W_intra->wta. 3004-3007: W_W_inter->wti.
// ============================================================================
__global__ __launch_bounds__(256) void k_gtab(
    const float* __restrict__ emb,
    const float* __restrict__ wih,   // [768][128]
    const float* __restrict__ bih,   // [768]
    const float* __restrict__ bhh,   // [768]
    const float* __restrict__ wwa,   // [256][256] h-major (intra)
    const float* __restrict__ wwi,   // [256][256] h-major (inter)
    unsigned short* __restrict__ gtab,   // [V][768] bf16
    unsigned short* __restrict__ wta,    // [256][256] bf16 n-major
    unsigned short* __restrict__ wti)    // [256][256] bf16 n-major
{
  __shared__ __align__(16) unsigned short smem[64 * 264];
  const int bid = blockIdx.x, tid = threadIdx.x;
  if (bid >= 3000) {  // LDS-tiled transpose, 64 n-rows per block
    const int tb = bid - 3000;
    const float* src = (tb < 4) ? wwa : wwi;
    unsigned short* dst = (tb < 4) ? wta : wti;
    const int n0 = (tb & 3) * 64;
    for (int i = 0; i < 64; ++i) {
      int cid = i * 256 + tid;
      int k = cid >> 6, nl = cid & 63;
      smem[nl * 264 + k] = f2b_rne(src[k * 256 + n0 + nl]);
    }
    __syncthreads();
    for (int i = 0; i < 8; ++i) {
      int cid = i * 256 + tid;
      int nl = cid >> 5, k8 = cid & 31;
      *(int4*)&dst[(size_t)(n0 + nl) * 256 + k8 * 8] =
          *(const int4*)&smem[nl * 264 + k8 * 8];
    }
    return;
  }
  const int mchunk = bid / 6, nchunk = bid % 6;
  const int vbase = mchunk * 64, nbase = nchunk * 128;
  for (int i = 0; i < 8; ++i) {
    int cid = i * 256 + tid;
    int row = cid >> 5, kc = cid & 31;
    float4 v = *(const float4*)&emb[(size_t)(vbase + row) * 128 + kc * 4];
    ushort4 u;
    u.x = f2b_rne(v.x); u.y = f2b_rne(v.y); u.z = f2b_rne(v.z); u.w = f2b_rne(v.w);
    *(ushort4*)&smem[row * 136 + kc * 4] = u;
  }
  __syncthreads();
  const int w = tid >> 6, l = tid & 63, q = l >> 4, ln = l & 15;
  s8v bf[2][4];
  float bias[2];
  for (int nt = 0; nt < 2; ++nt) {
    int c = nbase + (w * 2 + nt) * 16 + ln;
    int g = (c < 384) ? c : (c - 384);
    bias[nt] = bih[c] + (g < 256 ? bhh[c] : 0.f);
    for (int kf = 0; kf < 4; ++kf)
      bf[nt][kf] = cvt8(&wih[(size_t)c * 128 + kf * 32 + q * 8]);
  }
  for (int mt = 0; mt < 4; ++mt) {
    s8v af[4];
    for (int kf = 0; kf < 4; ++kf)
      af[kf] = *(const s8v*)&smem[(mt * 16 + ln) * 136 + kf * 32 + q * 8];
    for (int nt = 0; nt < 2; ++nt) {
      f32x4 acc = {0.f, 0.f, 0.f, 0.f};
      for (int kf = 0; kf < 4; ++kf) acc = mfma16(af[kf], bf[nt][kf], acc);
      const int col = nbase + (w * 2 + nt) * 16 + ln;
      for (int r = 0; r < 4; ++r) {
        const int row = vbase + mt * 16 + q * 4 + r;
        gtab[(size_t)row * 768 + col] = f2b_rne(acc[r] + bias[nt]);
      }
    }
  }
}

// ============================================================================
// K2: intra biGRU. Grid 256 = (s, dir, b-quad of 16). 256 thr = 4 waves;
// wave w owns h-dims [w*32,w*32+32) for all 3 gates (6 m-tiles, 24 MFMA/step).
// Double-buffered h in LDS, one LDS-only barrier/step, gather prefetched.
// ============================================================================
__global__ __launch_bounds__(256, 1) void k_intra(
    const int* __restrict__ tokens,
    const unsigned short* __restrict__ gtab,  // bf16, r/z biases folded
    const float* __restrict__ whh,            // [2][384][128]
    const float* __restrict__ bhh,            // [2][384]
    unsigned short* __restrict__ iout)        // [S*T*B][256] bf16
{
  const int bid = blockIdx.x;
  const int s = bid >> 3, dir = (bid >> 2) & 1, bq = bid & 3;
  const int bbase = bq * 16;
  const int tid = threadIdx.x;
  const int w = tid >> 6, l = tid & 63, q = l >> 4, ln = l & 15;
  const int d0 = w * 32;                      // wave's h-dim base

  __shared__ __align__(16) unsigned short hb[2][16 * 136];
  __shared__ int offs[T_ * 16];               // gtab byte offsets (incl dir)

  for (int i = tid; i < 2 * 16 * 136; i += 256) ((unsigned short*)hb)[i] = 0;
  for (int i = tid; i < T_ * 16; i += 256) {
    int t = i >> 4, bl = i & 15;
    offs[i] = tokens[(s * T_ + t) * B_ + bbase + bl] * 1536 + dir * 768;
  }

  s8v af[3][2][4];                            // [gate][dim-half][kf]
  float hbn[2][4];
  const float* whd = whh + (size_t)dir * (384 * 128);
  const float* bhd = bhh + dir * 384;
  for (int g3 = 0; g3 < 3; ++g3)
    for (int dt = 0; dt < 2; ++dt)
      for (int kf = 0; kf < 4; ++kf)
        af[g3][dt][kf] =
            cvt8(&whd[(size_t)(g3 * 128 + d0 + dt * 16 + ln) * 128 + kf * 32 + q * 8]);
  for (int dt = 0; dt < 2; ++dt)
    for (int r = 0; r < 4; ++r) hbn[dt][r] = bhd[256 + d0 + dt * 16 + q * 4 + r];
  float h[2][4] = {{0.f, 0.f, 0.f, 0.f}, {0.f, 0.f, 0.f, 0.f}};
  const int b = bbase + ln;
  const char* gbase = (const char*)gtab;
  const int lane_off = w * 64 + q * 8;        // byte offset of this lane's 4 dims
  __syncthreads();

  const int tfirst = dir ? (T_ - 1) : 0;
  const char* p0 = gbase + offs[tfirst * 16 + ln] + lane_off;
  ushort4 xr[2], xz[2], xn[2];
  for (int dt = 0; dt < 2; ++dt) {
    xr[dt] = *(const ushort4*)(p0 + dt * 32);
    xz[dt] = *(const ushort4*)(p0 + 256 + dt * 32);
    xn[dt] = *(const ushort4*)(p0 + 512 + dt * 32);
  }

  int p = 0;
  for (int step = 0; step < T_; ++step) {
    const int t = dir ? (T_ - 1 - step) : step;
    const int t1 = dir ? (t > 0 ? t - 1 : 0) : (t < T_ - 1 ? t + 1 : T_ - 1);
    const char* pn = gbase + offs[t1 * 16 + ln] + lane_off;
    ushort4 xrn[2], xzn[2], xnn[2];
    for (int dt = 0; dt < 2; ++dt) {
      xrn[dt] = *(const ushort4*)(pn + dt * 32);
      xzn[dt] = *(const ushort4*)(pn + 256 + dt * 32);
      xnn[dt] = *(const ushort4*)(pn + 512 + dt * 32);
    }

    s8v bfr[4];
    for (int kf = 0; kf < 4; ++kf)
      bfr[kf] = *(const s8v*)&hb[p][ln * 136 + kf * 32 + q * 8];
    f32x4 aR[2], aZ[2], aN[2];
    for (int dt = 0; dt < 2; ++dt) {
      aR[dt] = (f32x4){0.f, 0.f, 0.f, 0.f};
      aZ[dt] = (f32x4){0.f, 0.f, 0.f, 0.f};
      aN[dt] = (f32x4){0.f, 0.f, 0.f, 0.f};
    }
    for (int kf = 0; kf < 4; ++kf)
      for (int dt = 0; dt < 2; ++dt) {
        aR[dt] = mfma16(af[0][dt][kf], bfr[kf], aR[dt]);
        aZ[dt] = mfma16(af[1][dt][kf], bfr[kf], aZ[dt]);
        aN[dt] = mfma16(af[2][dt][kf], bfr[kf], aN[dt]);
      }

    for (int dt = 0; dt < 2; ++dt) {
      const unsigned short* xrp = (const unsigned short*)&xr[dt];
      const unsigned short* xzp = (const unsigned short*)&xz[dt];
      const unsigned short* xnp = (const unsigned short*)&xn[dt];
      unsigned short hnb[4];
      for (int r = 0; r < 4; ++r) {
        float rr = fsigm(b2f(xrp[r]) + aR[dt][r]);
        float zz = fsigm(b2f(xzp[r]) + aZ[dt][r]);
        float nn = ftanh(b2f(xnp[r]) + rr * (aN[dt][r] + hbn[dt][r]));
        float hv = zz * (h[dt][r] - nn) + nn;
        h[dt][r] = hv;
        hnb[r] = f2b(hv);
      }
      ushort4 hv4; hv4.x = hnb[0]; hv4.y = hnb[1]; hv4.z = hnb[2]; hv4.w = hnb[3];
      *(ushort4*)&hb[p ^ 1][ln * 136 + d0 + dt * 16 + q * 4] = hv4;
      *(ushort4*)&iout[((size_t)(s * T_ + t) * B_ + b) * 256 + dir * 128 + d0 +
                       dt * 16 + q * 4] = hv4;
    }
    lds_barrier();
    p ^= 1;
    for (int dt = 0; dt < 2; ++dt) { xr[dt] = xrn[dt]; xz[dt] = xzn[dt]; xn[dt] = xnn[dt]; }
  }
}

// ============================================================================
// K3a: partial a1 logits = proj . tanh(iout @ W_W_intra + b). 256 rows/block.
// ============================================================================
__global__ __launch_bounds__(256) void k_attn1(
    const unsigned short* __restrict__ iout,
    const unsigned short* __restrict__ wta,   // bf16 [256][256] n-major
    const float* __restrict__ bint,
    const float* __restrict__ proj,
    float* __restrict__ a1h, int half)
{
  __shared__ __align__(16) unsigned short wlds[128 * 256];  // 64 KB, XOR-swizzled
  const int tid = threadIdx.x, bid = blockIdx.x;
  const int nbg = half * 128;
  for (int i = 0; i < 16; ++i) {
    int cid = i * 256 + tid;
    int n = cid >> 5, kc = cid & 31;
    *(int4*)&wlds[n * 256 + ((kc ^ (n & 15)) << 3)] =
        *(const int4*)&wta[(size_t)(nbg + n) * 256 + kc * 8];
  }
  __syncthreads();
  const int w = tid >> 6, l = tid & 63, q = l >> 4, ln = l & 15;
  const int rbase = bid * 256;
  for (int mt4 = 0; mt4 < 4; ++mt4) {
    const int mt = w * 4 + mt4;
    const int rowa = rbase + mt * 16 + ln;
    s8v af[8];
    for (int kf = 0; kf < 8; ++kf)
      af[kf] = *(const s8v*)&iout[(size_t)rowa * 256 + kf * 32 + q * 8];
    float p0 = 0.f, p1 = 0.f, p2 = 0.f, p3 = 0.f;
    for (int nt = 0; nt < 8; ++nt) {
      const int nloc = nt * 16 + ln;
      f32x4 c = {0.f, 0.f, 0.f, 0.f};
      for (int kf = 0; kf < 8; ++kf) {
        s8v bf = *(const s8v*)&wlds[nloc * 256 + (((kf * 4 + q) ^ (nloc & 15)) << 3)];
        c = mfma16(af[kf], bf, c);
      }
      const int ncol = nbg + nloc;
      const float bb = bint[ncol], pp = proj[ncol];
      p0 += pp * ftanh(c[0] + bb);
      p1 += pp * ftanh(c[1] + bb);
      p2 += pp * ftanh(c[2] + bb);
      p3 += pp * ftanh(c[3] + bb);
    }
    for (int d = 1; d < 16; d <<= 1) {
      p0 += __shfl_xor(p0, d);
      p1 += __shfl_xor(p1, d);
      p2 += __shfl_xor(p2, d);
      p3 += __shfl_xor(p3, d);
    }
    if (ln == 0) {
      const int row = rbase + mt * 16 + q * 4;
      a1h[row] = p0; a1h[row + 1] = p1; a1h[row + 2] = p2; a1h[row + 3] = p3;
    }
  }
}

// ============================================================================
// K3b: softmax over T + weighted sum -> sent_vecs fp32 [S*B][256]
// ============================================================================
__global__ __launch_bounds__(256) void k_attn2(
    const float* __restrict__ a1p, const float* __restrict__ a1q,
    const unsigned short* __restrict__ iout,
    float* __restrict__ sv)
{
  const int bid = blockIdx.x;
  const int s = bid >> 6, b = bid & 63;
  const int tid = threadIdx.x;
  __shared__ float wgt[T_];
  if (tid < 64) {
    const int idx = (s * T_ + tid) * B_ + b;
    float lg = a1p[idx] + a1q[idx];
    float m = lg;
    for (int d = 1; d < 64; d <<= 1) m = fmaxf(m, __shfl_xor(m, d));
    float e = __builtin_amdgcn_exp2f(1.44269504f * (lg - m));
    float sum = e;
    for (int d = 1; d < 64; d <<= 1) sum += __shfl_xor(sum, d);
    wgt[tid] = e * __builtin_amdgcn_rcpf(sum);
  }
  __syncthreads();
  float acc = 0.f;
  for (int t = 0; t < T_; ++t)
    acc += wgt[t] * b2f(iout[((size_t)(s * T_ + t) * B_ + b) * 256 + tid]);
  sv[(size_t)(s * B_ + b) * 256 + tid] = acc;
}

// ============================================================================
// K4: xgi = sv @ Wih_inter^T + biases (r,z folded). MFMA GEMM M=2048 N=768
// K=256. Grid 192 = 32 m-chunks x 6 n-chunks. Output fp32 [2][2048][384].
// ============================================================================
__global__ __launch_bounds__(256) void k_xgi(
    const float* __restrict__ sv,
    const float* __restrict__ wihI,  // [768][256]
    const float* __restrict__ bihI,  // [768]
    const float* __restrict__ bhhI,  // [768]
    float* __restrict__ xgi)         // [2][2048][384]
{
  __shared__ __align__(16) unsigned short alds[64 * 264];
  const int bid = blockIdx.x, tid = threadIdx.x;
  const int mchunk = bid / 6, nchunk = bid % 6;
  const int vbase = mchunk * 64;
  const int dir = nchunk / 3, nb = (nchunk % 3) * 128;
  for (int i = 0; i < 16; ++i) {
    int cid = i * 256 + tid;
    int row = cid >> 6, kc = cid & 63;
    float4 v = *(const float4*)&sv[(size_t)(vbase + row) * 256 + kc * 4];
    ushort4 u;
    u.x = f2b_rne(v.x); u.y = f2b_rne(v.y); u.z = f2b_rne(v.z); u.w = f2b_rne(v.w);
    *(ushort4*)&alds[row * 264 + kc * 4] = u;
  }
  __syncthreads();
  const int w = tid >> 6, l = tid & 63, q = l >> 4, ln = l & 15;
  s8v bf[2][8];
  float bias[2];
  int gcol[2];
  for (int nt = 0; nt < 2; ++nt) {
    const int g = nb + (w * 2 + nt) * 16 + ln;
    const int c = dir * 384 + g;
    gcol[nt] = g;
    bias[nt] = bihI[c] + (g < 256 ? bhhI[c] : 0.f);
    for (int kf = 0; kf < 8; ++kf)
      bf[nt][kf] = cvt8(&wihI[(size_t)c * 256 + kf * 32 + q * 8]);
  }
  for (int mt = 0; mt < 4; ++mt) {
    s8v af[8];
    for (int kf = 0; kf < 8; ++kf)
      af[kf] = *(const s8v*)&alds[(mt * 16 + ln) * 264 + kf * 32 + q * 8];
    for (int nt = 0; nt < 2; ++nt) {
      f32x4 acc = {0.f, 0.f, 0.f, 0.f};
      for (int kf = 0; kf < 8; ++kf) acc = mfma16(af[kf], bf[nt][kf], acc);
      for (int r = 0; r < 4; ++r) {
        const int row = vbase + mt * 16 + q * 4 + r;
        xgi[((size_t)dir * 2048 + row) * 384 + gcol[nt]] = acc[r] + bias[nt];
      }
    }
  }
}

// ============================================================================
// K5: inter biGRU. Grid 8 = (dir, b-quad of 16). 4-wave pipeline as K2.
// ============================================================================
__global__ __launch_bounds__(256, 1) void k_inter(
    const float* __restrict__ xgi,   // r,z biases folded
    const float* __restrict__ whh,   // [2][384][128]
    const float* __restrict__ bhh,   // [2][384]
    float* __restrict__ io2)         // [S*B][256] fp32
{
  const int bid = blockIdx.x;
  const int dir = bid >> 2, bq = bid & 3, bbase = bq * 16;
  const int tid = threadIdx.x;
  const int w = tid >> 6, l = tid & 63, q = l >> 4, ln = l & 15;
  const int d0 = w * 32;
  __shared__ __align__(16) unsigned short hb[2][16 * 136];
  for (int i = tid; i < 2 * 16 * 136; i += 256) ((unsigned short*)hb)[i] = 0;
  s8v af[3][2][4];
  float hbn[2][4];
  const float* whd = whh + (size_t)dir * (384 * 128);
  const float* bhd = bhh + dir * 384;
  for (int g3 = 0; g3 < 3; ++g3)
    for (int dt = 0; dt < 2; ++dt)
      for (int kf = 0; kf < 4; ++kf)
        af[g3][dt][kf] =
            cvt8(&whd[(size_t)(g3 * 128 + d0 + dt * 16 + ln) * 128 + kf * 32 + q * 8]);
  for (int dt = 0; dt < 2; ++dt)
    for (int r = 0; r < 4; ++r) hbn[dt][r] = bhd[256 + d0 + dt * 16 + q * 4 + r];
  float h[2][4] = {{0.f, 0.f, 0.f, 0.f}, {0.f, 0.f, 0.f, 0.f}};
  const int b = bbase + ln;
  const int lo = d0 + q * 4;
  __syncthreads();

  const int sfirst = dir ? (S_ - 1) : 0;
  const float* xp0 = xgi + ((size_t)dir * 2048 + sfirst * 64 + b) * 384;
  float4 vr[2], vz[2], vn[2];
  for (int dt = 0; dt < 2; ++dt) {
    vr[dt] = *(const float4*)&xp0[lo + dt * 16];
    vz[dt] = *(const float4*)&xp0[128 + lo + dt * 16];
    vn[dt] = *(const float4*)&xp0[256 + lo + dt * 16];
  }

  int p = 0;
  for (int step = 0; step < S_; ++step) {
    const int sI = dir ? (S_ - 1 - step) : step;
    const int s1 = dir ? (sI > 0 ? sI - 1 : 0) : (sI < S_ - 1 ? sI + 1 : S_ - 1);
    const float* xpn = xgi + ((size_t)dir * 2048 + s1 * 64 + b) * 384;
    float4 vrn[2], vzn[2], vnn[2];
    for (int dt = 0; dt < 2; ++dt) {
      vrn[dt] = *(const float4*)&xpn[lo + dt * 16];
      vzn[dt] = *(const float4*)&xpn[128 + lo + dt * 16];
      vnn[dt] = *(const float4*)&xpn[256 + lo + dt * 16];
    }

    s8v bfr[4];
    for (int kf = 0; kf < 4; ++kf)
      bfr[kf] = *(const s8v*)&hb[p][ln * 136 + kf * 32 + q * 8];
    f32x4 aR[2], aZ[2], aN[2];
    for (int dt = 0; dt < 2; ++dt) {
      aR[dt] = (f32x4){0.f, 0.f, 0.f, 0.f};
      aZ[dt] = (f32x4){0.f, 0.f, 0.f, 0.f};
      aN[dt] = (f32x4){0.f, 0.f, 0.f, 0.f};
    }
    for (int kf = 0; kf < 4; ++kf)
      for (int dt = 0; dt < 2; ++dt) {
        aR[dt] = mfma16(af[0][dt][kf], bfr[kf], aR[dt]);
        aZ[dt] = mfma16(af[1][dt][kf], bfr[kf], aZ[dt]);
        aN[dt] = mfma16(af[2][dt][kf], bfr[kf], aN[dt]);
      }

    for (int dt = 0; dt < 2; ++dt) {
      const float* rv = (const float*)&vr[dt];
      const float* zv = (const float*)&vz[dt];
      const float* nv = (const float*)&vn[dt];
      unsigned short hnb[4];
      for (int r = 0; r < 4; ++r) {
        float rr = fsigm(rv[r] + aR[dt][r]);
        float zz = fsigm(zv[r] + aZ[dt][r]);
        float nn = ftanh(nv[r] + rr * (aN[dt][r] + hbn[dt][r]));
        float hv = zz * (h[dt][r] - nn) + nn;
        h[dt][r] = hv;
        hnb[r] = f2b(hv);
      }
      ushort4 hv4; hv4.x = hnb[0]; hv4.y = hnb[1]; hv4.z = hnb[2]; hv4.w = hnb[3];
      *(ushort4*)&hb[p ^ 1][ln * 136 + d0 + dt * 16 + q * 4] = hv4;
      float4 of4; of4.x = h[dt][0]; of4.y = h[dt][1]; of4.z = h[dt][2]; of4.w = h[dt][3];
      *(float4*)&io2[((size_t)(sI * 64 + b)) * 256 + dir * 128 + d0 + dt * 16 + q * 4] = of4;
    }
    lds_barrier();
    p ^= 1;
    for (int dt = 0; dt < 2; ++dt) { vr[dt] = vrn[dt]; vz[dt] = vzn[dt]; vn[dt] = vnn[dt]; }
  }
}

// ============================================================================
// K6: partial a2 = proj_inter . tanh(io2 @ W_W_inter + b_inter), MFMA,
// one N-half per launch, 64 rows/block (grid 32). k_final sums halves.
// ============================================================================
__global__ __launch_bounds__(256) void k_attn_i(
    const float* __restrict__ io2,            // [2048][256] fp32
    const unsigned short* __restrict__ wti,   // bf16 [256][256] n-major
    const float* __restrict__ bI,
    const float* __restrict__ projI,
    float* __restrict__ a2h, int half)
{
  __shared__ __align__(16) unsigned short wlds[128 * 256];
  const int tid = threadIdx.x, bid = blockIdx.x;
  const int nbg = half * 128;
  for (int i = 0; i < 16; ++i) {
    int cid = i * 256 + tid;
    int n = cid >> 5, kc = cid & 31;
    *(int4*)&wlds[n * 256 + ((kc ^ (n & 15)) << 3)] =
        *(const int4*)&wti[(size_t)(nbg + n) * 256 + kc * 8];
  }
  __syncthreads();
  const int w = tid >> 6, l = tid & 63, q = l >> 4, ln = l & 15;
  const int row = bid * 64 + w * 16 + ln;
  s8v af[8];
  for (int kf = 0; kf < 8; ++kf)
    af[kf] = cvt8(&io2[(size_t)row * 256 + kf * 32 + q * 8]);
  float p0 = 0.f, p1 = 0.f, p2 = 0.f, p3 = 0.f;
  for (int nt = 0; nt < 8; ++nt) {
    const int nloc = nt * 16 + ln;
    f32x4 c = {0.f, 0.f, 0.f, 0.f};
    for (int kf = 0; kf < 8; ++kf) {
      s8v bf = *(const s8v*)&wlds[nloc * 256 + (((kf * 4 + q) ^ (nloc & 15)) << 3)];
      c = mfma16(af[kf], bf, c);
    }
    const int ncol = nbg + nloc;
    const float bb = bI[ncol], pp = projI[ncol];
    p0 += pp * ftanh(c[0] + bb);
    p1 += pp * ftanh(c[1] + bb);
    p2 += pp * ftanh(c[2] + bb);
    p3 += pp * ftanh(c[3] + bb);
  }
  for (int d = 1; d < 16; d <<= 1) {
    p0 += __shfl_xor(p0, d);
    p1 += __shfl_xor(p1, d);
    p2 += __shfl_xor(p2, d);
    p3 += __shfl_xor(p3, d);
  }
  if (ln == 0) {
    const int r0 = bid * 64 + w * 16 + q * 4;
    a2h[r0] = p0; a2h[r0 + 1] = p1; a2h[r0 + 2] = p2; a2h[r0 + 3] = p3;
  }
}

// ============================================================================
// K7: doc_vec = sum_s a2 * io2 ; out = doc @ W_final^T + b_final
// ============================================================================
__global__ __launch_bounds__(256) void k_final(
    const float* __restrict__ a2p, const float* __restrict__ a2q,
    const float* __restrict__ io2,
    const float* __restrict__ wf,    // [5][256]
    const float* __restrict__ bfi,   // [5]
    float* __restrict__ out)         // [64][5]
{
  const int b = blockIdx.x, tid = threadIdx.x;
  __shared__ float av[S_];
  __shared__ float dv[256];
  __shared__ float red[4];
  if (tid < S_) av[tid] = a2p[tid * 64 + b] + a2q[tid * 64 + b];
  __syncthreads();
  float acc = 0.f;
  for (int s = 0; s < S_; ++s) acc += av[s] * io2[((size_t)(s * 64 + b)) * 256 + tid];
  dv[tid] = acc;
  __syncthreads();
  for (int c = 0; c < C_; ++c) {
    float pv = wf[c * 256 + tid] * dv[tid];
    for (int d = 1; d < 64; d <<= 1) pv += __shfl_xor(pv, d);
    const int w = tid >> 6, l = tid & 63;
    if (l == 0) red[w] = pv;
    __syncthreads();
    if (tid == 0)
      out[b * C_ + c] = red[0] + red[1] + red[2] + red[3] + bfi[c];
    __syncthreads();
  }
}

// ============================================================================
extern "C" void kernel_launch(void* const* d_in, const int* in_sizes, int n_in,
                              void* d_out, int out_size, void* d_ws, size_t ws_size,
                              hipStream_t stream) {
  (void)in_sizes; (void)n_in; (void)out_size; (void)ws_size;
  const int*   tokens = (const int*)d_in[0];
  const float* emb    = (const float*)d_in[1];
  const float* wih_a  = (const float*)d_in[2];
  const float* whh_a  = (const float*)d_in[3];
  const float* bih_a  = (const float*)d_in[4];
  const float* bhh_a  = (const float*)d_in[5];
  const float* ww_a   = (const float*)d_in[6];
  const float* b_a    = (const float*)d_in[7];
  const float* proj_a = (const float*)d_in[8];
  const float* wih_i  = (const float*)d_in[9];
  const float* whh_i  = (const float*)d_in[10];
  const float* bih_i  = (const float*)d_in[11];
  const float* bhh_i  = (const float*)d_in[12];
  const float* ww_i   = (const float*)d_in[13];
  const float* b_i    = (const float*)d_in[14];
  const float* proj_i = (const float*)d_in[15];
  const float* w_fin  = (const float*)d_in[16];
  const float* b_fin  = (const float*)d_in[17];

  char* ws = (char*)d_ws;
  unsigned short* gtab = (unsigned short*)(ws + 0);          // 49,152,000
  unsigned short* wta  = (unsigned short*)(ws + 49152000);   //    131,072
  unsigned short* iout = (unsigned short*)(ws + 49283072);   // 67,108,864
  float* a1p = (float*)(ws + 116391936);                     //    524,288
  float* a1q = (float*)(ws + 116916224);                     //    524,288
  float* sv  = (float*)(ws + 117440512);                     //  2,097,152
  float* xgi = (float*)(ws + 119537664);                     //  6,291,456
  float* io2 = (float*)(ws + 125829120);                     //  2,097,152
  float* a2p = (float*)(ws + 127926272);                     //      8,192
  float* a2q = (float*)(ws + 127934464);                     //      8,192
  unsigned short* wti = (unsigned short*)(ws + 127942656);   //    131,072

  k_gtab<<<3008, 256, 0, stream>>>(emb, wih_a, bih_a, bhh_a, ww_a, ww_i,
                                   gtab, wta, wti);
  k_intra<<<256, 256, 0, stream>>>(tokens, gtab, whh_a, bhh_a, iout);
  k_attn1<<<512, 256, 0, stream>>>(iout, wta, b_a, proj_a, a1p, 0);
  k_attn1<<<512, 256, 0, stream>>>(iout, wta, b_a, proj_a, a1q, 1);
  k_attn2<<<2048, 256, 0, stream>>>(a1p, a1q, iout, sv);
  k_xgi<<<192, 256, 0, stream>>>(sv, wih_i, bih_i, bhh_i, xgi);
  k_inter<<<8, 256, 0, stream>>>(xgi, whh_i, bhh_i, io2);
  k_attn_i<<<32, 256, 0, stream>>>(io2, wti, b_i, proj_i, a2p, 0);
  k_attn_i<<<32, 256, 0, stream>>>(io2, wti, b_i, proj_i, a2q, 1);
  k_final<<<64, 256, 0, stream>>>(a2p, a2q, io2, w_fin, b_fin, (float*)d_out);
}

// Round 6
// 411.202 us; speedup vs baseline: 1.0112x; 1.0112x over previous
//
#include <hip/hip_runtime.h>

// Problem dims
#define S_ 32
#define T_ 64
#define B_ 64
#define V_ 32000
#define E_ 128
#define H_ 128
#define G_ 128
#define C_ 5

typedef short s8v __attribute__((ext_vector_type(8)));   // 8 bf16 payload
typedef __bf16 b8v __attribute__((ext_vector_type(8)));
typedef float f32x4 __attribute__((ext_vector_type(4)));

// --- MFMA wrapper: tolerate either builtin operand signature (short8 or bf16x8)
template <typename V>
__device__ inline auto mfma_sel(V a, V b, f32x4 c, int)
    -> decltype(__builtin_amdgcn_mfma_f32_16x16x32_bf16(a, b, c, 0, 0, 0)) {
  return __builtin_amdgcn_mfma_f32_16x16x32_bf16(a, b, c, 0, 0, 0);
}
template <typename V>
__device__ inline f32x4 mfma_sel(V a, V b, f32x4 c, long) {
  return __builtin_amdgcn_mfma_f32_16x16x32_bf16(
      __builtin_bit_cast(b8v, a), __builtin_bit_cast(b8v, b), c, 0, 0, 0);
}
__device__ inline f32x4 mfma16(s8v a, s8v b, f32x4 c) { return mfma_sel(a, b, c, 0); }

__device__ inline float b2f(unsigned short u) {
  union { unsigned int i; float f; } v; v.i = ((unsigned int)u) << 16; return v.f;
}
// round-to-nearest (ties away) — 2 instr
__device__ inline unsigned short f2b(float f) {
  union { float f; unsigned int i; } v; v.f = f;
  return (unsigned short)((v.i + 0x8000u) >> 16);
}
// full-RNE for precomputed tables
__device__ inline unsigned short f2b_rne(float f) {
  union { float f; unsigned int i; } v; v.f = f;
  unsigned int r = (v.i + 0x7fffu + ((v.i >> 16) & 1u)) >> 16;
  return (unsigned short)r;
}
__device__ inline s8v cvt8(const float* p) {
  const float4 a = *(const float4*)p;
  const float4 b = *(const float4*)(p + 4);
  s8v r;
  r[0] = (short)f2b_rne(a.x); r[1] = (short)f2b_rne(a.y);
  r[2] = (short)f2b_rne(a.z); r[3] = (short)f2b_rne(a.w);
  r[4] = (short)f2b_rne(b.x); r[5] = (short)f2b_rne(b.y);
  r[6] = (short)f2b_rne(b.z); r[7] = (short)f2b_rne(b.w);
  return r;
}
// division-free activations (v_rcp_f32 + v_exp_f32; exact saturation at +-inf)
__device__ inline float fsigm(float x) {
  return __builtin_amdgcn_rcpf(1.f + __builtin_amdgcn_exp2f(-1.44269504f * x));
}
__device__ inline float ftanh(float x) {
  return 1.f - 2.f * __builtin_amdgcn_rcpf(1.f + __builtin_amdgcn_exp2f(2.88539008f * x));
}
// LDS-only barrier: global loads stay in flight across it
__device__ inline void lds_barrier() {
  asm volatile("s_waitcnt lgkmcnt(0)\n\ts_barrier" ::: "memory");
}

// ============================================================================
// K1: gtab = emb @ Wih_intra^T + bih (+bhh r,z folded). MFMA GEMM with
// LDS-staged output tile -> 16B/lane coalesced gtab stores.
// Blocks 3000-3003: transpose W_W_intra->wta. 3004-3007: W_W_inter->wti.
// ============================================================================
__global__ __launch_bounds__(256) void k_gtab(
    const float* __restrict__ emb,
    const float* __restrict__ wih,   // [768][128]
    const float* __restrict__ bih,   // [768]
    const float* __restrict__ bhh,   // [768]
    const float* __restrict__ wwa,   // [256][256] h-major (intra)
    const float* __restrict__ wwi,   // [256][256] h-major (inter)
    unsigned short* __restrict__ gtab,   // [V][768] bf16
    unsigned short* __restrict__ wta,    // [256][256] bf16 n-major
    unsigned short* __restrict__ wti)    // [256][256] bf16 n-major
{
  __shared__ __align__(16) unsigned short smem[64 * 264];  // A-tile / transpose
  __shared__ __align__(16) unsigned short obuf[64 * 136];  // staged C-tile
  const int bid = blockIdx.x, tid = threadIdx.x;
  if (bid >= 3000) {  // LDS-tiled transpose, 64 n-rows per block
    const int tb = bid - 3000;
    const float* src = (tb < 4) ? wwa : wwi;
    unsigned short* dst = (tb < 4) ? wta : wti;
    const int n0 = (tb & 3) * 64;
    for (int i = 0; i < 64; ++i) {
      int cid = i * 256 + tid;
      int k = cid >> 6, nl = cid & 63;
      smem[nl * 264 + k] = f2b_rne(src[k * 256 + n0 + nl]);
    }
    __syncthreads();
    for (int i = 0; i < 8; ++i) {
      int cid = i * 256 + tid;
      int nl = cid >> 5, k8 = cid & 31;
      *(int4*)&dst[(size_t)(n0 + nl) * 256 + k8 * 8] =
          *(const int4*)&smem[nl * 264 + k8 * 8];
    }
    return;
  }
  const int mchunk = bid / 6, nchunk = bid % 6;
  const int vbase = mchunk * 64, nbase = nchunk * 128;
  for (int i = 0; i < 8; ++i) {
    int cid = i * 256 + tid;
    int row = cid >> 5, kc = cid & 31;
    float4 v = *(const float4*)&emb[(size_t)(vbase + row) * 128 + kc * 4];
    ushort4 u;
    u.x = f2b_rne(v.x); u.y = f2b_rne(v.y); u.z = f2b_rne(v.z); u.w = f2b_rne(v.w);
    *(ushort4*)&smem[row * 136 + kc * 4] = u;
  }
  __syncthreads();
  const int w = tid >> 6, l = tid & 63, q = l >> 4, ln = l & 15;
  s8v bf[2][4];
  float bias[2];
  for (int nt = 0; nt < 2; ++nt) {
    int c = nbase + (w * 2 + nt) * 16 + ln;
    int g = (c < 384) ? c : (c - 384);
    bias[nt] = bih[c] + (g < 256 ? bhh[c] : 0.f);
    for (int kf = 0; kf < 4; ++kf)
      bf[nt][kf] = cvt8(&wih[(size_t)c * 128 + kf * 32 + q * 8]);
  }
  for (int mt = 0; mt < 4; ++mt) {
    s8v af[4];
    for (int kf = 0; kf < 4; ++kf)
      af[kf] = *(const s8v*)&smem[(mt * 16 + ln) * 136 + kf * 32 + q * 8];
    for (int nt = 0; nt < 2; ++nt) {
      f32x4 acc = {0.f, 0.f, 0.f, 0.f};
      for (int kf = 0; kf < 4; ++kf) acc = mfma16(af[kf], bf[nt][kf], acc);
      const int colL = (w * 2 + nt) * 16 + ln;
      for (int r = 0; r < 4; ++r)
        obuf[(mt * 16 + q * 4 + r) * 136 + colL] = f2b_rne(acc[r] + bias[nt]);
    }
  }
  __syncthreads();
  // coalesced store: 64 rows x 256B contiguous
  for (int i = 0; i < 4; ++i) {
    int cid = i * 256 + tid;
    int row = cid >> 4, chunk = cid & 15;
    *(int4*)&gtab[(size_t)(vbase + row) * 768 + nbase + chunk * 8] =
        *(const int4*)&obuf[row * 136 + chunk * 8];
  }
}

// ============================================================================
// K2: intra biGRU. Grid 512 = (s, dir, b-octet of 8) -> 2 blocks/CU
// (__launch_bounds__(256,2)); lanes 8-15 duplicate lanes 0-7 (same per-wave
// issue, stall-hiding via co-resident block). 4 waves x 32 h-dims. One
// LDS-only barrier/step, next-step gate gather prefetched.
// ============================================================================
__global__ __launch_bounds__(256, 2) void k_intra(
    const int* __restrict__ tokens,
    const unsigned short* __restrict__ gtab,  // bf16, r/z biases folded
    const float* __restrict__ whh,            // [2][384][128]
    const float* __restrict__ bhh,            // [2][384]
    unsigned short* __restrict__ iout)        // [S*T*B][256] bf16
{
  const int bid = blockIdx.x;
  const int s = bid >> 4, dir = (bid >> 3) & 1, bq = bid & 7;
  const int bbase = bq * 8;
  const int tid = threadIdx.x;
  const int w = tid >> 6, l = tid & 63, q = l >> 4, ln = l & 15;
  const int tln = ln & 7;
  const int d0 = w * 32;                      // wave's h-dim base

  __shared__ __align__(16) unsigned short hb[2][16 * 136];
  __shared__ int offs[T_ * 8];                // gtab byte offsets (incl dir)

  for (int i = tid; i < 2 * 16 * 136; i += 256) ((unsigned short*)hb)[i] = 0;
  for (int i = tid; i < T_ * 8; i += 256) {
    int t = i >> 3, bl = i & 7;
    offs[i] = tokens[(s * T_ + t) * B_ + bbase + bl] * 1536 + dir * 768;
  }

  s8v af[3][2][4];                            // [gate][dim-half][kf]
  float hbn[2][4];
  const float* whd = whh + (size_t)dir * (384 * 128);
  const float* bhd = bhh + dir * 384;
  for (int g3 = 0; g3 < 3; ++g3)
    for (int dt = 0; dt < 2; ++dt)
      for (int kf = 0; kf < 4; ++kf)
        af[g3][dt][kf] =
            cvt8(&whd[(size_t)(g3 * 128 + d0 + dt * 16 + ln) * 128 + kf * 32 + q * 8]);
  for (int dt = 0; dt < 2; ++dt)
    for (int r = 0; r < 4; ++r) hbn[dt][r] = bhd[256 + d0 + dt * 16 + q * 4 + r];
  float h[2][4] = {{0.f, 0.f, 0.f, 0.f}, {0.f, 0.f, 0.f, 0.f}};
  const int b = bbase + tln;
  const char* gb = (const char*)gtab;
  const int lane_off = w * 64 + q * 8;        // byte offset of lane's 4 dims
  __syncthreads();

  const int tfirst = dir ? (T_ - 1) : 0;
  const char* p0 = gb + offs[tfirst * 8 + tln] + lane_off;
  ushort4 xr[2], xz[2], xn[2];
  for (int dt = 0; dt < 2; ++dt) {
    xr[dt] = *(const ushort4*)(p0 + dt * 32);
    xz[dt] = *(const ushort4*)(p0 + 256 + dt * 32);
    xn[dt] = *(const ushort4*)(p0 + 512 + dt * 32);
  }

  int p = 0;
  for (int step = 0; step < T_; ++step) {
    const int t = dir ? (T_ - 1 - step) : step;
    const int t1 = dir ? (t > 0 ? t - 1 : 0) : (t < T_ - 1 ? t + 1 : T_ - 1);
    const char* pn = gb + offs[t1 * 8 + tln] + lane_off;
    ushort4 xrn[2], xzn[2], xnn[2];
    for (int dt = 0; dt < 2; ++dt) {
      xrn[dt] = *(const ushort4*)(pn + dt * 32);
      xzn[dt] = *(const ushort4*)(pn + 256 + dt * 32);
      xnn[dt] = *(const ushort4*)(pn + 512 + dt * 32);
    }

    s8v bfr[4];
    for (int kf = 0; kf < 4; ++kf)
      bfr[kf] = *(const s8v*)&hb[p][ln * 136 + kf * 32 + q * 8];
    f32x4 aR[2], aZ[2], aN[2];
    for (int dt = 0; dt < 2; ++dt) {
      aR[dt] = (f32x4){0.f, 0.f, 0.f, 0.f};
      aZ[dt] = (f32x4){0.f, 0.f, 0.f, 0.f};
      aN[dt] = (f32x4){0.f, 0.f, 0.f, 0.f};
    }
    for (int kf = 0; kf < 4; ++kf)
      for (int dt = 0; dt < 2; ++dt) {
        aR[dt] = mfma16(af[0][dt][kf], bfr[kf], aR[dt]);
        aZ[dt] = mfma16(af[1][dt][kf], bfr[kf], aZ[dt]);
        aN[dt] = mfma16(af[2][dt][kf], bfr[kf], aN[dt]);
      }

    for (int dt = 0; dt < 2; ++dt) {
      const unsigned short* xrp = (const unsigned short*)&xr[dt];
      const unsigned short* xzp = (const unsigned short*)&xz[dt];
      const unsigned short* xnp = (const unsigned short*)&xn[dt];
      unsigned short hnb[4];
      for (int r = 0; r < 4; ++r) {
        float rr = fsigm(b2f(xrp[r]) + aR[dt][r]);
        float zz = fsigm(b2f(xzp[r]) + aZ[dt][r]);
        float nn = ftanh(b2f(xnp[r]) + rr * (aN[dt][r] + hbn[dt][r]));
        float hv = zz * (h[dt][r] - nn) + nn;
        h[dt][r] = hv;
        hnb[r] = f2b(hv);
      }
      ushort4 hv4; hv4.x = hnb[0]; hv4.y = hnb[1]; hv4.z = hnb[2]; hv4.w = hnb[3];
      *(ushort4*)&hb[p ^ 1][ln * 136 + d0 + dt * 16 + q * 4] = hv4;
      if (ln < 8)
        *(ushort4*)&iout[((size_t)(s * T_ + t) * B_ + b) * 256 + dir * 128 + d0 +
                         dt * 16 + q * 4] = hv4;
    }
    lds_barrier();
    p ^= 1;
    for (int dt = 0; dt < 2; ++dt) { xr[dt] = xrn[dt]; xz[dt] = xzn[dt]; xn[dt] = xnn[dt]; }
  }
}

// ============================================================================
// K3a: a1 = proj . tanh(iout @ W_W_intra + b), FULL N=256 in one launch:
// N staged in two 64KB LDS halves, proj-dot accumulated across halves.
// ONE pass over iout (A-frags re-read for half 1 hit L2). Grid 512.
// ============================================================================
__global__ __launch_bounds__(256) void k_attn1(
    const unsigned short* __restrict__ iout,
    const unsigned short* __restrict__ wta,   // bf16 [256 n][256 k]
    const float* __restrict__ bint,
    const float* __restrict__ proj,
    float* __restrict__ a1)
{
  __shared__ __align__(16) unsigned short wlds[128 * 256];  // 64 KB, swizzled
  const int tid = threadIdx.x, bid = blockIdx.x;
  const int w = tid >> 6, l = tid & 63, q = l >> 4, ln = l & 15;
  const int rbase = bid * 256;
  float pr[4][4];
  for (int m = 0; m < 4; ++m)
    for (int r = 0; r < 4; ++r) pr[m][r] = 0.f;
  for (int half = 0; half < 2; ++half) {
    const int nbg = half * 128;
    __syncthreads();  // protect previous half's reads
    for (int i = 0; i < 16; ++i) {
      int cid = i * 256 + tid;
      int n = cid >> 5, kc = cid & 31;
      *(int4*)&wlds[n * 256 + ((kc ^ (n & 15)) << 3)] =
          *(const int4*)&wta[(size_t)(nbg + n) * 256 + kc * 8];
    }
    __syncthreads();
    for (int mt4 = 0; mt4 < 4; ++mt4) {
      const int rowa = rbase + (w * 4 + mt4) * 16 + ln;
      s8v af[8];
      for (int kf = 0; kf < 8; ++kf)
        af[kf] = *(const s8v*)&iout[(size_t)rowa * 256 + kf * 32 + q * 8];
      for (int nt = 0; nt < 8; ++nt) {
        const int nloc = nt * 16 + ln;
        f32x4 c = {0.f, 0.f, 0.f, 0.f};
        for (int kf = 0; kf < 8; ++kf) {
          s8v bf = *(const s8v*)&wlds[nloc * 256 + (((kf * 4 + q) ^ (nloc & 15)) << 3)];
          c = mfma16(af[kf], bf, c);
        }
        const int ncol = nbg + nloc;
        const float bb = bint[ncol], pp = proj[ncol];
        pr[mt4][0] += pp * ftanh(c[0] + bb);
        pr[mt4][1] += pp * ftanh(c[1] + bb);
        pr[mt4][2] += pp * ftanh(c[2] + bb);
        pr[mt4][3] += pp * ftanh(c[3] + bb);
      }
    }
  }
  for (int mt4 = 0; mt4 < 4; ++mt4) {
    float p0 = pr[mt4][0], p1 = pr[mt4][1], p2 = pr[mt4][2], p3 = pr[mt4][3];
    for (int d = 1; d < 16; d <<= 1) {
      p0 += __shfl_xor(p0, d);
      p1 += __shfl_xor(p1, d);
      p2 += __shfl_xor(p2, d);
      p3 += __shfl_xor(p3, d);
    }
    if (ln == 0) {
      const int row = rbase + (w * 4 + mt4) * 16 + q * 4;
      a1[row] = p0; a1[row + 1] = p1; a1[row + 2] = p2; a1[row + 3] = p3;
    }
  }
}

// ============================================================================
// K3b: softmax over T + weighted sum -> sent_vecs fp32 [S*B][256]
// ============================================================================
__global__ __launch_bounds__(256) void k_attn2(
    const float* __restrict__ a1,
    const unsigned short* __restrict__ iout,
    float* __restrict__ sv)
{
  const int bid = blockIdx.x;
  const int s = bid >> 6, b = bid & 63;
  const int tid = threadIdx.x;
  __shared__ float wgt[T_];
  if (tid < 64) {
    float lg = a1[(s * T_ + tid) * B_ + b];
    float m = lg;
    for (int d = 1; d < 64; d <<= 1) m = fmaxf(m, __shfl_xor(m, d));
    float e = __builtin_amdgcn_exp2f(1.44269504f * (lg - m));
    float sum = e;
    for (int d = 1; d < 64; d <<= 1) sum += __shfl_xor(sum, d);
    wgt[tid] = e * __builtin_amdgcn_rcpf(sum);
  }
  __syncthreads();
  float acc = 0.f;
  for (int t = 0; t < T_; ++t)
    acc += wgt[t] * b2f(iout[((size_t)(s * T_ + t) * B_ + b) * 256 + tid]);
  sv[(size_t)(s * B_ + b) * 256 + tid] = acc;
}

// ============================================================================
// K4: xgi = sv @ Wih_inter^T + biases (r,z folded). MFMA GEMM. Grid 192.
// ============================================================================
__global__ __launch_bounds__(256) void k_xgi(
    const float* __restrict__ sv,
    const float* __restrict__ wihI,  // [768][256]
    const float* __restrict__ bihI,  // [768]
    const float* __restrict__ bhhI,  // [768]
    float* __restrict__ xgi)         // [2][2048][384]
{
  __shared__ __align__(16) unsigned short alds[64 * 264];
  const int bid = blockIdx.x, tid = threadIdx.x;
  const int mchunk = bid / 6, nchunk = bid % 6;
  const int vbase = mchunk * 64;
  const int dir = nchunk / 3, nb = (nchunk % 3) * 128;
  for (int i = 0; i < 16; ++i) {
    int cid = i * 256 + tid;
    int row = cid >> 6, kc = cid & 63;
    float4 v = *(const float4*)&sv[(size_t)(vbase + row) * 256 + kc * 4];
    ushort4 u;
    u.x = f2b_rne(v.x); u.y = f2b_rne(v.y); u.z = f2b_rne(v.z); u.w = f2b_rne(v.w);
    *(ushort4*)&alds[row * 264 + kc * 4] = u;
  }
  __syncthreads();
  const int w = tid >> 6, l = tid & 63, q = l >> 4, ln = l & 15;
  s8v bf[2][8];
  float bias[2];
  int gcol[2];
  for (int nt = 0; nt < 2; ++nt) {
    const int g = nb + (w * 2 + nt) * 16 + ln;
    const int c = dir * 384 + g;
    gcol[nt] = g;
    bias[nt] = bihI[c] + (g < 256 ? bhhI[c] : 0.f);
    for (int kf = 0; kf < 8; ++kf)
      bf[nt][kf] = cvt8(&wihI[(size_t)c * 256 + kf * 32 + q * 8]);
  }
  for (int mt = 0; mt < 4; ++mt) {
    s8v af[8];
    for (int kf = 0; kf < 8; ++kf)
      af[kf] = *(const s8v*)&alds[(mt * 16 + ln) * 264 + kf * 32 + q * 8];
    for (int nt = 0; nt < 2; ++nt) {
      f32x4 acc = {0.f, 0.f, 0.f, 0.f};
      for (int kf = 0; kf < 8; ++kf) acc = mfma16(af[kf], bf[nt][kf], acc);
      for (int r = 0; r < 4; ++r) {
        const int row = vbase + mt * 16 + q * 4 + r;
        xgi[((size_t)dir * 2048 + row) * 384 + gcol[nt]] = acc[r] + bias[nt];
      }
    }
  }
}

// ============================================================================
// K5: inter biGRU. Grid 8 = (dir, b-quad of 16). 4-wave pipeline as K2.
// ============================================================================
__global__ __launch_bounds__(256, 1) void k_inter(
    const float* __restrict__ xgi,   // r,z biases folded
    const float* __restrict__ whh,   // [2][384][128]
    const float* __restrict__ bhh,   // [2][384]
    float* __restrict__ io2)         // [S*B][256] fp32
{
  const int bid = blockIdx.x;
  const int dir = bid >> 2, bq = bid & 3, bbase = bq * 16;
  const int tid = threadIdx.x;
  const int w = tid >> 6, l = tid & 63, q = l >> 4, ln = l & 15;
  const int d0 = w * 32;
  __shared__ __align__(16) unsigned short hb[2][16 * 136];
  for (int i = tid; i < 2 * 16 * 136; i += 256) ((unsigned short*)hb)[i] = 0;
  s8v af[3][2][4];
  float hbn[2][4];
  const float* whd = whh + (size_t)dir * (384 * 128);
  const float* bhd = bhh + dir * 384;
  for (int g3 = 0; g3 < 3; ++g3)
    for (int dt = 0; dt < 2; ++dt)
      for (int kf = 0; kf < 4; ++kf)
        af[g3][dt][kf] =
            cvt8(&whd[(size_t)(g3 * 128 + d0 + dt * 16 + ln) * 128 + kf * 32 + q * 8]);
  for (int dt = 0; dt < 2; ++dt)
    for (int r = 0; r < 4; ++r) hbn[dt][r] = bhd[256 + d0 + dt * 16 + q * 4 + r];
  float h[2][4] = {{0.f, 0.f, 0.f, 0.f}, {0.f, 0.f, 0.f, 0.f}};
  const int b = bbase + ln;
  const int lo = d0 + q * 4;
  __syncthreads();

  const int sfirst = dir ? (S_ - 1) : 0;
  const float* xp0 = xgi + ((size_t)dir * 2048 + sfirst * 64 + b) * 384;
  float4 vr[2], vz[2], vn[2];
  for (int dt = 0; dt < 2; ++dt) {
    vr[dt] = *(const float4*)&xp0[lo + dt * 16];
    vz[dt] = *(const float4*)&xp0[128 + lo + dt * 16];
    vn[dt] = *(const float4*)&xp0[256 + lo + dt * 16];
  }

  int p = 0;
  for (int step = 0; step < S_; ++step) {
    const int sI = dir ? (S_ - 1 - step) : step;
    const int s1 = dir ? (sI > 0 ? sI - 1 : 0) : (sI < S_ - 1 ? sI + 1 : S_ - 1);
    const float* xpn = xgi + ((size_t)dir * 2048 + s1 * 64 + b) * 384;
    float4 vrn[2], vzn[2], vnn[2];
    for (int dt = 0; dt < 2; ++dt) {
      vrn[dt] = *(const float4*)&xpn[lo + dt * 16];
      vzn[dt] = *(const float4*)&xpn[128 + lo + dt * 16];
      vnn[dt] = *(const float4*)&xpn[256 + lo + dt * 16];
    }

    s8v bfr[4];
    for (int kf = 0; kf < 4; ++kf)
      bfr[kf] = *(const s8v*)&hb[p][ln * 136 + kf * 32 + q * 8];
    f32x4 aR[2], aZ[2], aN[2];
    for (int dt = 0; dt < 2; ++dt) {
      aR[dt] = (f32x4){0.f, 0.f, 0.f, 0.f};
      aZ[dt] = (f32x4){0.f, 0.f, 0.f, 0.f};
      aN[dt] = (f32x4){0.f, 0.f, 0.f, 0.f};
    }
    for (int kf = 0; kf < 4; ++kf)
      for (int dt = 0; dt < 2; ++dt) {
        aR[dt] = mfma16(af[0][dt][kf], bfr[kf], aR[dt]);
        aZ[dt] = mfma16(af[1][dt][kf], bfr[kf], aZ[dt]);
        aN[dt] = mfma16(af[2][dt][kf], bfr[kf], aN[dt]);
      }

    for (int dt = 0; dt < 2; ++dt) {
      const float* rv = (const float*)&vr[dt];
      const float* zv = (const float*)&vz[dt];
      const float* nv = (const float*)&vn[dt];
      unsigned short hnb[4];
      for (int r = 0; r < 4; ++r) {
        float rr = fsigm(rv[r] + aR[dt][r]);
        float zz = fsigm(zv[r] + aZ[dt][r]);
        float nn = ftanh(nv[r] + rr * (aN[dt][r] + hbn[dt][r]));
        float hv = zz * (h[dt][r] - nn) + nn;
        h[dt][r] = hv;
        hnb[r] = f2b(hv);
      }
      ushort4 hv4; hv4.x = hnb[0]; hv4.y = hnb[1]; hv4.z = hnb[2]; hv4.w = hnb[3];
      *(ushort4*)&hb[p ^ 1][ln * 136 + d0 + dt * 16 + q * 4] = hv4;
      float4 of4; of4.x = h[dt][0]; of4.y = h[dt][1]; of4.z = h[dt][2]; of4.w = h[dt][3];
      *(float4*)&io2[((size_t)(sI * 64 + b)) * 256 + dir * 128 + d0 + dt * 16 + q * 4] = of4;
    }
    lds_barrier();
    p ^= 1;
    for (int dt = 0; dt < 2; ++dt) { vr[dt] = vrn[dt]; vz[dt] = vzn[dt]; vn[dt] = vnn[dt]; }
  }
}

// ============================================================================
// K6: partial a2 = proj_inter . tanh(io2 @ W_W_inter + b_inter). One launch,
// grid 64: bid>>5 selects N-half, bid&31 selects 64-row chunk.
// ============================================================================
__global__ __launch_bounds__(256) void k_attn_i(
    const float* __restrict__ io2,            // [2048][256] fp32
    const unsigned short* __restrict__ wti,   // bf16 [256][256] n-major
    const float* __restrict__ bI,
    const float* __restrict__ projI,
    float* __restrict__ a2p, float* __restrict__ a2q)
{
  __shared__ __align__(16) unsigned short wlds[128 * 256];
  const int tid = threadIdx.x, bid = blockIdx.x;
  const int half = bid >> 5, bچ = bid & 31;
  float* a2h = half ? a2q : a2p;
  const int nbg = half * 128;
  for (int i = 0; i < 16; ++i) {
    int cid = i * 256 + tid;
    int n = cid >> 5, kc = cid & 31;
    *(int4*)&wlds[n * 256 + ((kc ^ (n & 15)) << 3)] =
        *(const int4*)&wti[(size_t)(nbg + n) * 256 + kc * 8];
  }
  __syncthreads();
  const int w = tid >> 6, l = tid & 63, q = l >> 4, ln = l & 15;
  const int row = bچ * 64 + w * 16 + ln;
  s8v af[8];
  for (int kf = 0; kf < 8; ++kf)
    af[kf] = cvt8(&io2[(size_t)row * 256 + kf * 32 + q * 8]);
  float p0 = 0.f, p1 = 0.f, p2 = 0.f, p3 = 0.f;
  for (int nt = 0; nt < 8; ++nt) {
    const int nloc = nt * 16 + ln;
    f32x4 c = {0.f, 0.f, 0.f, 0.f};
    for (int kf = 0; kf < 8; ++kf) {
      s8v bf = *(const s8v*)&wlds[nloc * 256 + (((kf * 4 + q) ^ (nloc & 15)) << 3)];
      c = mfma16(af[kf], bf, c);
    }
    const int ncol = nbg + nloc;
    const float bb = bI[ncol], pp = projI[ncol];
    p0 += pp * ftanh(c[0] + bb);
    p1 += pp * ftanh(c[1] + bb);
    p2 += pp * ftanh(c[2] + bb);
    p3 += pp * ftanh(c[3] + bb);
  }
  for (int d = 1; d < 16; d <<= 1) {
    p0 += __shfl_xor(p0, d);
    p1 += __shfl_xor(p1, d);
    p2 += __shfl_xor(p2, d);
    p3 += __shfl_xor(p3, d);
  }
  if (ln == 0) {
    const int r0 = bچ * 64 + w * 16 + q * 4;
    a2h[r0] = p0; a2h[r0 + 1] = p1; a2h[r0 + 2] = p2; a2h[r0 + 3] = p3;
  }
}

// ============================================================================
// K7: doc_vec = sum_s a2 * io2 ; out = doc @ W_final^T + b_final
// ============================================================================
__global__ __launch_bounds__(256) void k_final(
    const float* __restrict__ a2p, const float* __restrict__ a2q,
    const float* __restrict__ io2,
    const float* __restrict__ wf,    // [5][256]
    const float* __restrict__ bfi,   // [5]
    float* __restrict__ out)         // [64][5]
{
  const int b = blockIdx.x, tid = threadIdx.x;
  __shared__ float av[S_];
  __shared__ float dv[256];
  __shared__ float red[4];
  if (tid < S_) av[tid] = a2p[tid * 64 + b] + a2q[tid * 64 + b];
  __syncthreads();
  float acc = 0.f;
  for (int s = 0; s < S_; ++s) acc += av[s] * io2[((size_t)(s * 64 + b)) * 256 + tid];
  dv[tid] = acc;
  __syncthreads();
  for (int c = 0; c < C_; ++c) {
    float pv = wf[c * 256 + tid] * dv[tid];
    for (int d = 1; d < 64; d <<= 1) pv += __shfl_xor(pv, d);
    const int w = tid >> 6, l = tid & 63;
    if (l == 0) red[w] = pv;
    __syncthreads();
    if (tid == 0)
      out[b * C_ + c] = red[0] + red[1] + red[2] + red[3] + bfi[c];
    __syncthreads();
  }
}

// ============================================================================
extern "C" void kernel_launch(void* const* d_in, const int* in_sizes, int n_in,
                              void* d_out, int out_size, void* d_ws, size_t ws_size,
                              hipStream_t stream) {
  (void)in_sizes; (void)n_in; (void)out_size; (void)ws_size;
  const int*   tokens = (const int*)d_in[0];
  const float* emb    = (const float*)d_in[1];
  const float* wih_a  = (const float*)d_in[2];
  const float* whh_a  = (const float*)d_in[3];
  const float* bih_a  = (const float*)d_in[4];
  const float* bhh_a  = (const float*)d_in[5];
  const float* ww_a   = (const float*)d_in[6];
  const float* b_a    = (const float*)d_in[7];
  const float* proj_a = (const float*)d_in[8];
  const float* wih_i  = (const float*)d_in[9];
  const float* whh_i  = (const float*)d_in[10];
  const float* bih_i  = (const float*)d_in[11];
  const float* bhh_i  = (const float*)d_in[12];
  const float* ww_i   = (const float*)d_in[13];
  const float* b_i    = (const float*)d_in[14];
  const float* proj_i = (const float*)d_in[15];
  const float* w_fin  = (const float*)d_in[16];
  const float* b_fin  = (const float*)d_in[17];

  char* ws = (char*)d_ws;
  unsigned short* gtab = (unsigned short*)(ws + 0);          // 49,152,000
  unsigned short* wta  = (unsigned short*)(ws + 49152000);   //    131,072
  unsigned short* iout = (unsigned short*)(ws + 49283072);   // 67,108,864
  float* a1  = (float*)(ws + 116391936);                     //    524,288
  float* sv  = (float*)(ws + 117440512);                     //  2,097,152
  float* xgi = (float*)(ws + 119537664);                     //  6,291,456
  float* io2 = (float*)(ws + 125829120);                     //  2,097,152
  float* a2p = (float*)(ws + 127926272);                     //      8,192
  float* a2q = (float*)(ws + 127934464);                     //      8,192
  unsigned short* wti = (unsigned short*)(ws + 127942656);   //    131,072

  k_gtab<<<3008, 256, 0, stream>>>(emb, wih_a, bih_a, bhh_a, ww_a, ww_i,
                                   gtab, wta, wti);
  k_intra<<<512, 256, 0, stream>>>(tokens, gtab, whh_a, bhh_a, iout);
  k_attn1<<<512, 256, 0, stream>>>(iout, wta, b_a, proj_a, a1);
  k_attn2<<<2048, 256, 0, stream>>>(a1, iout, sv);
  k_xgi<<<192, 256, 0, stream>>>(sv, wih_i, bih_i, bhh_i, xgi);
  k_inter<<<8, 256, 0, stream>>>(xgi, whh_i, bhh_i, io2);
  k_attn_i<<<64, 256, 0, stream>>>(io2, wti, b_i, proj_i, a2p, a2q);
  k_final<<<64, 256, 0, stream>>>(a2p, a2q, io2, w_fin, b_fin, (float*)d_out);
}

// Round 7
// 374.858 us; speedup vs baseline: 1.1092x; 1.0970x over previous
//
#include <hip/hip_runtime.h>

// Problem dims
#define S_ 32
#define T_ 64
#define B_ 64
#define V_ 32000
#define E_ 128
#define H_ 128
#define G_ 128
#define C_ 5

typedef short s8v __attribute__((ext_vector_type(8)));   // 8 bf16 payload
typedef __bf16 b8v __attribute__((ext_vector_type(8)));
typedef float f32x4 __attribute__((ext_vector_type(4)));

// --- MFMA wrapper: tolerate either builtin operand signature (short8 or bf16x8)
template <typename V>
__device__ inline auto mfma_sel(V a, V b, f32x4 c, int)
    -> decltype(__builtin_amdgcn_mfma_f32_16x16x32_bf16(a, b, c, 0, 0, 0)) {
  return __builtin_amdgcn_mfma_f32_16x16x32_bf16(a, b, c, 0, 0, 0);
}
template <typename V>
__device__ inline f32x4 mfma_sel(V a, V b, f32x4 c, long) {
  return __builtin_amdgcn_mfma_f32_16x16x32_bf16(
      __builtin_bit_cast(b8v, a), __builtin_bit_cast(b8v, b), c, 0, 0, 0);
}
__device__ inline f32x4 mfma16(s8v a, s8v b, f32x4 c) { return mfma_sel(a, b, c, 0); }

__device__ inline float b2f(unsigned short u) {
  union { unsigned int i; float f; } v; v.i = ((unsigned int)u) << 16; return v.f;
}
// round-to-nearest (ties away) — 2 instr
__device__ inline unsigned short f2b(float f) {
  union { float f; unsigned int i; } v; v.f = f;
  return (unsigned short)((v.i + 0x8000u) >> 16);
}
// full-RNE for precomputed tables
__device__ inline unsigned short f2b_rne(float f) {
  union { float f; unsigned int i; } v; v.f = f;
  unsigned int r = (v.i + 0x7fffu + ((v.i >> 16) & 1u)) >> 16;
  return (unsigned short)r;
}
__device__ inline s8v cvt8(const float* p) {
  const float4 a = *(const float4*)p;
  const float4 b = *(const float4*)(p + 4);
  s8v r;
  r[0] = (short)f2b_rne(a.x); r[1] = (short)f2b_rne(a.y);
  r[2] = (short)f2b_rne(a.z); r[3] = (short)f2b_rne(a.w);
  r[4] = (short)f2b_rne(b.x); r[5] = (short)f2b_rne(b.y);
  r[6] = (short)f2b_rne(b.z); r[7] = (short)f2b_rne(b.w);
  return r;
}
// division-free activations (v_rcp_f32 + v_exp_f32; exact saturation at +-inf)
__device__ inline float fsigm(float x) {
  return __builtin_amdgcn_rcpf(1.f + __builtin_amdgcn_exp2f(-1.44269504f * x));
}
__device__ inline float ftanh(float x) {
  return 1.f - 2.f * __builtin_amdgcn_rcpf(1.f + __builtin_amdgcn_exp2f(2.88539008f * x));
}
// LDS-only barrier: global loads stay in flight across it
__device__ inline void lds_barrier() {
  asm volatile("s_waitcnt lgkmcnt(0)\n\ts_barrier" ::: "memory");
}

// ============================================================================
// K1: gtab = emb @ Wih_intra^T + bih (+bhh r,z folded). MFMA GEMM with
// LDS-staged output tile -> coalesced gtab stores.
// Blocks 3000-3003: transpose W_W_intra->wta. 3004-3007: W_W_inter->wti.
// ============================================================================
__global__ __launch_bounds__(256) void k_gtab(
    const float* __restrict__ emb,
    const float* __restrict__ wih,   // [768][128]
    const float* __restrict__ bih,   // [768]
    const float* __restrict__ bhh,   // [768]
    const float* __restrict__ wwa,   // [256][256] h-major (intra)
    const float* __restrict__ wwi,   // [256][256] h-major (inter)
    unsigned short* __restrict__ gtab,   // [V][768] bf16
    unsigned short* __restrict__ wta,    // [256][256] bf16 n-major
    unsigned short* __restrict__ wti)    // [256][256] bf16 n-major
{
  __shared__ __align__(16) unsigned short smem[64 * 264];  // A-tile / transpose
  __shared__ __align__(16) unsigned short obuf[64 * 136];  // staged C-tile
  const int bid = blockIdx.x, tid = threadIdx.x;
  if (bid >= 3000) {  // LDS-tiled transpose, 64 n-rows per block
    const int tb = bid - 3000;
    const float* src = (tb < 4) ? wwa : wwi;
    unsigned short* dst = (tb < 4) ? wta : wti;
    const int n0 = (tb & 3) * 64;
    for (int i = 0; i < 64; ++i) {
      int cid = i * 256 + tid;
      int k = cid >> 6, nl = cid & 63;
      smem[nl * 264 + k] = f2b_rne(src[k * 256 + n0 + nl]);
    }
    __syncthreads();
    for (int i = 0; i < 8; ++i) {
      int cid = i * 256 + tid;
      int nl = cid >> 5, k8 = cid & 31;
      *(int4*)&dst[(size_t)(n0 + nl) * 256 + k8 * 8] =
          *(const int4*)&smem[nl * 264 + k8 * 8];
    }
    return;
  }
  const int mchunk = bid / 6, nchunk = bid % 6;
  const int vbase = mchunk * 64, nbase = nchunk * 128;
  for (int i = 0; i < 8; ++i) {
    int cid = i * 256 + tid;
    int row = cid >> 5, kc = cid & 31;
    float4 v = *(const float4*)&emb[(size_t)(vbase + row) * 128 + kc * 4];
    ushort4 u;
    u.x = f2b_rne(v.x); u.y = f2b_rne(v.y); u.z = f2b_rne(v.z); u.w = f2b_rne(v.w);
    *(ushort4*)&smem[row * 136 + kc * 4] = u;
  }
  __syncthreads();
  const int w = tid >> 6, l = tid & 63, q = l >> 4, ln = l & 15;
  s8v bf[2][4];
  float bias[2];
  for (int nt = 0; nt < 2; ++nt) {
    int c = nbase + (w * 2 + nt) * 16 + ln;
    int g = (c < 384) ? c : (c - 384);
    bias[nt] = bih[c] + (g < 256 ? bhh[c] : 0.f);
    for (int kf = 0; kf < 4; ++kf)
      bf[nt][kf] = cvt8(&wih[(size_t)c * 128 + kf * 32 + q * 8]);
  }
  for (int mt = 0; mt < 4; ++mt) {
    s8v af[4];
    for (int kf = 0; kf < 4; ++kf)
      af[kf] = *(const s8v*)&smem[(mt * 16 + ln) * 136 + kf * 32 + q * 8];
    for (int nt = 0; nt < 2; ++nt) {
      f32x4 acc = {0.f, 0.f, 0.f, 0.f};
      for (int kf = 0; kf < 4; ++kf) acc = mfma16(af[kf], bf[nt][kf], acc);
      const int colL = (w * 2 + nt) * 16 + ln;
      for (int r = 0; r < 4; ++r)
        obuf[(mt * 16 + q * 4 + r) * 136 + colL] = f2b_rne(acc[r] + bias[nt]);
    }
  }
  __syncthreads();
  for (int i = 0; i < 4; ++i) {
    int cid = i * 256 + tid;
    int row = cid >> 4, chunk = cid & 15;
    *(int4*)&gtab[(size_t)(vbase + row) * 768 + nbase + chunk * 8] =
        *(const int4*)&obuf[row * 136 + chunk * 8];
  }
}

// ============================================================================
// K2: intra biGRU. Grid 256 = (s, dir, b-quad of 16), 256 thr = 4 waves,
// wave w owns h-dims [32w,32w+32) x 3 gates. Double-buffered h in LDS, one
// LDS-only barrier/step. Gate gather prefetched TWO steps ahead (3 register
// sets) so L3/HBM latency is fully covered; bfr ds_read + MFMA issued first
// each step (critical path before prefetch address math).
// ============================================================================
__global__ __launch_bounds__(256, 1) void k_intra(
    const int* __restrict__ tokens,
    const unsigned short* __restrict__ gtab,  // bf16, r/z biases folded
    const float* __restrict__ whh,            // [2][384][128]
    const float* __restrict__ bhh,            // [2][384]
    unsigned short* __restrict__ iout)        // [S*T*B][256] bf16
{
  const int bid = blockIdx.x;
  const int s = bid >> 3, dir = (bid >> 2) & 1, bq = bid & 3;
  const int bbase = bq * 16;
  const int tid = threadIdx.x;
  const int w = tid >> 6, l = tid & 63, q = l >> 4, ln = l & 15;
  const int d0 = w * 32;                      // wave's h-dim base

  __shared__ __align__(16) unsigned short hb[2][16 * 136];
  __shared__ int offs[T_ * 16];               // gtab byte offsets (incl dir)

  for (int i = tid; i < 2 * 16 * 136; i += 256) ((unsigned short*)hb)[i] = 0;
  for (int i = tid; i < T_ * 16; i += 256) {
    int t = i >> 4, bl = i & 15;
    offs[i] = tokens[(s * T_ + t) * B_ + bbase + bl] * 1536 + dir * 768;
  }

  s8v af[3][2][4];                            // [gate][dim-half][kf]
  float hbn[2][4];
  const float* whd = whh + (size_t)dir * (384 * 128);
  const float* bhd = bhh + dir * 384;
  for (int g3 = 0; g3 < 3; ++g3)
    for (int dt = 0; dt < 2; ++dt)
      for (int kf = 0; kf < 4; ++kf)
        af[g3][dt][kf] =
            cvt8(&whd[(size_t)(g3 * 128 + d0 + dt * 16 + ln) * 128 + kf * 32 + q * 8]);
  for (int dt = 0; dt < 2; ++dt)
    for (int r = 0; r < 4; ++r) hbn[dt][r] = bhd[256 + d0 + dt * 16 + q * 4 + r];
  float h[2][4] = {{0.f, 0.f, 0.f, 0.f}, {0.f, 0.f, 0.f, 0.f}};
  const int b = bbase + ln;
  const char* gb = (const char*)gtab;
  const int lane_off = w * 64 + q * 8;        // byte offset of lane's 4 dims
  __syncthreads();

  // --- 2-deep software pipeline of the gate gather ---
  // set 0 = step 0, set 1 = step 1; per-iteration we load step+2.
  ushort4 xr0[2], xz0[2], xn0[2], xr1[2], xz1[2], xn1[2];
  {
    const int ta = dir ? (T_ - 1) : 0;
    const int tb = dir ? (T_ - 2) : 1;
    const char* pa = gb + offs[ta * 16 + ln] + lane_off;
    const char* pb = gb + offs[tb * 16 + ln] + lane_off;
    for (int dt = 0; dt < 2; ++dt) {
      xr0[dt] = *(const ushort4*)(pa + dt * 32);
      xz0[dt] = *(const ushort4*)(pa + 256 + dt * 32);
      xn0[dt] = *(const ushort4*)(pa + 512 + dt * 32);
      xr1[dt] = *(const ushort4*)(pb + dt * 32);
      xz1[dt] = *(const ushort4*)(pb + 256 + dt * 32);
      xn1[dt] = *(const ushort4*)(pb + 512 + dt * 32);
    }
  }

  int p = 0;
  for (int step = 0; step < T_; ++step) {
    const int t = dir ? (T_ - 1 - step) : step;

    // ---- critical path first: h read + MFMA issue ----
    s8v bfr[4];
    for (int kf = 0; kf < 4; ++kf)
      bfr[kf] = *(const s8v*)&hb[p][ln * 136 + kf * 32 + q * 8];
    f32x4 aR[2], aZ[2], aN[2];
    for (int dt = 0; dt < 2; ++dt) {
      aR[dt] = (f32x4){0.f, 0.f, 0.f, 0.f};
      aZ[dt] = (f32x4){0.f, 0.f, 0.f, 0.f};
      aN[dt] = (f32x4){0.f, 0.f, 0.f, 0.f};
    }
    for (int kf = 0; kf < 4; ++kf)
      for (int dt = 0; dt < 2; ++dt) {
        aR[dt] = mfma16(af[0][dt][kf], bfr[kf], aR[dt]);
        aZ[dt] = mfma16(af[1][dt][kf], bfr[kf], aZ[dt]);
        aN[dt] = mfma16(af[2][dt][kf], bfr[kf], aN[dt]);
      }

    // ---- prefetch step+2 (consumed two barriers later) ----
    const int sp2 = (step + 2 < T_) ? step + 2 : T_ - 1;
    const int t2 = dir ? (T_ - 1 - sp2) : sp2;
    const char* pc = gb + offs[t2 * 16 + ln] + lane_off;
    ushort4 xr2[2], xz2[2], xn2[2];
    for (int dt = 0; dt < 2; ++dt) {
      xr2[dt] = *(const ushort4*)(pc + dt * 32);
      xz2[dt] = *(const ushort4*)(pc + 256 + dt * 32);
      xn2[dt] = *(const ushort4*)(pc + 512 + dt * 32);
    }

    // ---- cell math consumes set 0 ----
    for (int dt = 0; dt < 2; ++dt) {
      const unsigned short* xrp = (const unsigned short*)&xr0[dt];
      const unsigned short* xzp = (const unsigned short*)&xz0[dt];
      const unsigned short* xnp = (const unsigned short*)&xn0[dt];
      unsigned short hnb[4];
      for (int r = 0; r < 4; ++r) {
        float rr = fsigm(b2f(xrp[r]) + aR[dt][r]);
        float zz = fsigm(b2f(xzp[r]) + aZ[dt][r]);
        float nn = ftanh(b2f(xnp[r]) + rr * (aN[dt][r] + hbn[dt][r]));
        float hv = zz * (h[dt][r] - nn) + nn;
        h[dt][r] = hv;
        hnb[r] = f2b(hv);
      }
      ushort4 hv4; hv4.x = hnb[0]; hv4.y = hnb[1]; hv4.z = hnb[2]; hv4.w = hnb[3];
      *(ushort4*)&hb[p ^ 1][ln * 136 + d0 + dt * 16 + q * 4] = hv4;
      *(ushort4*)&iout[((size_t)(s * T_ + t) * B_ + b) * 256 + dir * 128 + d0 +
                       dt * 16 + q * 4] = hv4;
    }
    lds_barrier();
    p ^= 1;
    // rotate pipeline registers
    for (int dt = 0; dt < 2; ++dt) {
      xr0[dt] = xr1[dt]; xz0[dt] = xz1[dt]; xn0[dt] = xn1[dt];
      xr1[dt] = xr2[dt]; xz1[dt] = xz2[dt]; xn1[dt] = xn2[dt];
    }
  }
}

// ============================================================================
// K3a: a1 = proj . tanh(iout @ W_W_intra + b), FULL N=256 in one launch:
// N staged in two 64KB LDS halves, proj-dot accumulated across halves.
// ============================================================================
__global__ __launch_bounds__(256) void k_attn1(
    const unsigned short* __restrict__ iout,
    const unsigned short* __restrict__ wta,   // bf16 [256 n][256 k]
    const float* __restrict__ bint,
    const float* __restrict__ proj,
    float* __restrict__ a1)
{
  __shared__ __align__(16) unsigned short wlds[128 * 256];  // 64 KB, swizzled
  const int tid = threadIdx.x, bid = blockIdx.x;
  const int w = tid >> 6, l = tid & 63, q = l >> 4, ln = l & 15;
  const int rbase = bid * 256;
  float pr[4][4];
  for (int m = 0; m < 4; ++m)
    for (int r = 0; r < 4; ++r) pr[m][r] = 0.f;
  for (int half = 0; half < 2; ++half) {
    const int nbg = half * 128;
    __syncthreads();  // protect previous half's reads
    for (int i = 0; i < 16; ++i) {
      int cid = i * 256 + tid;
      int n = cid >> 5, kc = cid & 31;
      *(int4*)&wlds[n * 256 + ((kc ^ (n & 15)) << 3)] =
          *(const int4*)&wta[(size_t)(nbg + n) * 256 + kc * 8];
    }
    __syncthreads();
    for (int mt4 = 0; mt4 < 4; ++mt4) {
      const int rowa = rbase + (w * 4 + mt4) * 16 + ln;
      s8v af[8];
      for (int kf = 0; kf < 8; ++kf)
        af[kf] = *(const s8v*)&iout[(size_t)rowa * 256 + kf * 32 + q * 8];
      for (int nt = 0; nt < 8; ++nt) {
        const int nloc = nt * 16 + ln;
        f32x4 c = {0.f, 0.f, 0.f, 0.f};
        for (int kf = 0; kf < 8; ++kf) {
          s8v bf = *(const s8v*)&wlds[nloc * 256 + (((kf * 4 + q) ^ (nloc & 15)) << 3)];
          c = mfma16(af[kf], bf, c);
        }
        const int ncol = nbg + nloc;
        const float bb = bint[ncol], pp = proj[ncol];
        pr[mt4][0] += pp * ftanh(c[0] + bb);
        pr[mt4][1] += pp * ftanh(c[1] + bb);
        pr[mt4][2] += pp * ftanh(c[2] + bb);
        pr[mt4][3] += pp * ftanh(c[3] + bb);
      }
    }
  }
  for (int mt4 = 0; mt4 < 4; ++mt4) {
    float p0 = pr[mt4][0], p1 = pr[mt4][1], p2 = pr[mt4][2], p3 = pr[mt4][3];
    for (int d = 1; d < 16; d <<= 1) {
      p0 += __shfl_xor(p0, d);
      p1 += __shfl_xor(p1, d);
      p2 += __shfl_xor(p2, d);
      p3 += __shfl_xor(p3, d);
    }
    if (ln == 0) {
      const int row = rbase + (w * 4 + mt4) * 16 + q * 4;
      a1[row] = p0; a1[row + 1] = p1; a1[row + 2] = p2; a1[row + 3] = p3;
    }
  }
}

// ============================================================================
// K3b: softmax over T + weighted sum -> sent_vecs fp32 [S*B][256]
// ============================================================================
__global__ __launch_bounds__(256) void k_attn2(
    const float* __restrict__ a1,
    const unsigned short* __restrict__ iout,
    float* __restrict__ sv)
{
  const int bid = blockIdx.x;
  const int s = bid >> 6, b = bid & 63;
  const int tid = threadIdx.x;
  __shared__ float wgt[T_];
  if (tid < 64) {
    float lg = a1[(s * T_ + tid) * B_ + b];
    float m = lg;
    for (int d = 1; d < 64; d <<= 1) m = fmaxf(m, __shfl_xor(m, d));
    float e = __builtin_amdgcn_exp2f(1.44269504f * (lg - m));
    float sum = e;
    for (int d = 1; d < 64; d <<= 1) sum += __shfl_xor(sum, d);
    wgt[tid] = e * __builtin_amdgcn_rcpf(sum);
  }
  __syncthreads();
  float acc = 0.f;
  for (int t = 0; t < T_; ++t)
    acc += wgt[t] * b2f(iout[((size_t)(s * T_ + t) * B_ + b) * 256 + tid]);
  sv[(size_t)(s * B_ + b) * 256 + tid] = acc;
}

// ============================================================================
// K4: xgi = sv @ Wih_inter^T + biases (r,z folded). MFMA GEMM. Grid 192.
// ============================================================================
__global__ __launch_bounds__(256) void k_xgi(
    const float* __restrict__ sv,
    const float* __restrict__ wihI,  // [768][256]
    const float* __restrict__ bihI,  // [768]
    const float* __restrict__ bhhI,  // [768]
    float* __restrict__ xgi)         // [2][2048][384]
{
  __shared__ __align__(16) unsigned short alds[64 * 264];
  const int bid = blockIdx.x, tid = threadIdx.x;
  const int mchunk = bid / 6, nchunk = bid % 6;
  const int vbase = mchunk * 64;
  const int dir = nchunk / 3, nb = (nchunk % 3) * 128;
  for (int i = 0; i < 16; ++i) {
    int cid = i * 256 + tid;
    int row = cid >> 6, kc = cid & 63;
    float4 v = *(const float4*)&sv[(size_t)(vbase + row) * 256 + kc * 4];
    ushort4 u;
    u.x = f2b_rne(v.x); u.y = f2b_rne(v.y); u.z = f2b_rne(v.z); u.w = f2b_rne(v.w);
    *(ushort4*)&alds[row * 264 + kc * 4] = u;
  }
  __syncthreads();
  const int w = tid >> 6, l = tid & 63, q = l >> 4, ln = l & 15;
  s8v bf[2][8];
  float bias[2];
  int gcol[2];
  for (int nt = 0; nt < 2; ++nt) {
    const int g = nb + (w * 2 + nt) * 16 + ln;
    const int c = dir * 384 + g;
    gcol[nt] = g;
    bias[nt] = bihI[c] + (g < 256 ? bhhI[c] : 0.f);
    for (int kf = 0; kf < 8; ++kf)
      bf[nt][kf] = cvt8(&wihI[(size_t)c * 256 + kf * 32 + q * 8]);
  }
  for (int mt = 0; mt < 4; ++mt) {
    s8v af[8];
    for (int kf = 0; kf < 8; ++kf)
      af[kf] = *(const s8v*)&alds[(mt * 16 + ln) * 264 + kf * 32 + q * 8];
    for (int nt = 0; nt < 2; ++nt) {
      f32x4 acc = {0.f, 0.f, 0.f, 0.f};
      for (int kf = 0; kf < 8; ++kf) acc = mfma16(af[kf], bf[nt][kf], acc);
      for (int r = 0; r < 4; ++r) {
        const int row = vbase + mt * 16 + q * 4 + r;
        xgi[((size_t)dir * 2048 + row) * 384 + gcol[nt]] = acc[r] + bias[nt];
      }
    }
  }
}

// ============================================================================
// K5: inter biGRU. Grid 8 = (dir, b-quad of 16). 4-wave pipeline as K2,
// with 2-step-ahead xgi prefetch.
// ============================================================================
__global__ __launch_bounds__(256, 1) void k_inter(
    const float* __restrict__ xgi,   // r,z biases folded
    const float* __restrict__ whh,   // [2][384][128]
    const float* __restrict__ bhh,   // [2][384]
    float* __restrict__ io2)         // [S*B][256] fp32
{
  const int bid = blockIdx.x;
  const int dir = bid >> 2, bq = bid & 3, bbase = bq * 16;
  const int tid = threadIdx.x;
  const int w = tid >> 6, l = tid & 63, q = l >> 4, ln = l & 15;
  const int d0 = w * 32;
  __shared__ __align__(16) unsigned short hb[2][16 * 136];
  for (int i = tid; i < 2 * 16 * 136; i += 256) ((unsigned short*)hb)[i] = 0;
  s8v af[3][2][4];
  float hbn[2][4];
  const float* whd = whh + (size_t)dir * (384 * 128);
  const float* bhd = bhh + dir * 384;
  for (int g3 = 0; g3 < 3; ++g3)
    for (int dt = 0; dt < 2; ++dt)
      for (int kf = 0; kf < 4; ++kf)
        af[g3][dt][kf] =
            cvt8(&whd[(size_t)(g3 * 128 + d0 + dt * 16 + ln) * 128 + kf * 32 + q * 8]);
  for (int dt = 0; dt < 2; ++dt)
    for (int r = 0; r < 4; ++r) hbn[dt][r] = bhd[256 + d0 + dt * 16 + q * 4 + r];
  float h[2][4] = {{0.f, 0.f, 0.f, 0.f}, {0.f, 0.f, 0.f, 0.f}};
  const int b = bbase + ln;
  const int lo = d0 + q * 4;
  __syncthreads();

  auto xrow = [&](int si) {
    si = (si < S_ - 1) ? si : S_ - 1;
    const int sI = dir ? (S_ - 1 - si) : si;
    return xgi + ((size_t)dir * 2048 + sI * 64 + b) * 384;
  };
  float4 vr0[2], vz0[2], vn0[2], vr1[2], vz1[2], vn1[2];
  {
    const float* pa = xrow(0);
    const float* pb = xrow(1);
    for (int dt = 0; dt < 2; ++dt) {
      vr0[dt] = *(const float4*)&pa[lo + dt * 16];
      vz0[dt] = *(const float4*)&pa[128 + lo + dt * 16];
      vn0[dt] = *(const float4*)&pa[256 + lo + dt * 16];
      vr1[dt] = *(const float4*)&pb[lo + dt * 16];
      vz1[dt] = *(const float4*)&pb[128 + lo + dt * 16];
      vn1[dt] = *(const float4*)&pb[256 + lo + dt * 16];
    }
  }

  int p = 0;
  for (int step = 0; step < S_; ++step) {
    const int sI = dir ? (S_ - 1 - step) : step;

    s8v bfr[4];
    for (int kf = 0; kf < 4; ++kf)
      bfr[kf] = *(const s8v*)&hb[p][ln * 136 + kf * 32 + q * 8];
    f32x4 aR[2], aZ[2], aN[2];
    for (int dt = 0; dt < 2; ++dt) {
      aR[dt] = (f32x4){0.f, 0.f, 0.f, 0.f};
      aZ[dt] = (f32x4){0.f, 0.f, 0.f, 0.f};
      aN[dt] = (f32x4){0.f, 0.f, 0.f, 0.f};
    }
    for (int kf = 0; kf < 4; ++kf)
      for (int dt = 0; dt < 2; ++dt) {
        aR[dt] = mfma16(af[0][dt][kf], bfr[kf], aR[dt]);
        aZ[dt] = mfma16(af[1][dt][kf], bfr[kf], aZ[dt]);
        aN[dt] = mfma16(af[2][dt][kf], bfr[kf], aN[dt]);
      }

    const float* pc = xrow(step + 2);
    float4 vr2[2], vz2[2], vn2[2];
    for (int dt = 0; dt < 2; ++dt) {
      vr2[dt] = *(const float4*)&pc[lo + dt * 16];
      vz2[dt] = *(const float4*)&pc[128 + lo + dt * 16];
      vn2[dt] = *(const float4*)&pc[256 + lo + dt * 16];
    }

    for (int dt = 0; dt < 2; ++dt) {
      const float* rv = (const float*)&vr0[dt];
      const float* zv = (const float*)&vz0[dt];
      const float* nv = (const float*)&vn0[dt];
      unsigned short hnb[4];
      for (int r = 0; r < 4; ++r) {
        float rr = fsigm(rv[r] + aR[dt][r]);
        float zz = fsigm(zv[r] + aZ[dt][r]);
        float nn = ftanh(nv[r] + rr * (aN[dt][r] + hbn[dt][r]));
        float hv = zz * (h[dt][r] - nn) + nn;
        h[dt][r] = hv;
        hnb[r] = f2b(hv);
      }
      ushort4 hv4; hv4.x = hnb[0]; hv4.y = hnb[1]; hv4.z = hnb[2]; hv4.w = hnb[3];
      *(ushort4*)&hb[p ^ 1][ln * 136 + d0 + dt * 16 + q * 4] = hv4;
      float4 of4; of4.x = h[dt][0]; of4.y = h[dt][1]; of4.z = h[dt][2]; of4.w = h[dt][3];
      *(float4*)&io2[((size_t)(sI * 64 + b)) * 256 + dir * 128 + d0 + dt * 16 + q * 4] = of4;
    }
    lds_barrier();
    p ^= 1;
    for (int dt = 0; dt < 2; ++dt) {
      vr0[dt] = vr1[dt]; vz0[dt] = vz1[dt]; vn0[dt] = vn1[dt];
      vr1[dt] = vr2[dt]; vz1[dt] = vz2[dt]; vn1[dt] = vn2[dt];
    }
  }
}

// ============================================================================
// K6: partial a2 = proj_inter . tanh(io2 @ W_W_inter + b_inter). One launch,
// grid 64: bid>>5 selects N-half, bid&31 selects 64-row chunk.
// ============================================================================
__global__ __launch_bounds__(256) void k_attn_i(
    const float* __restrict__ io2,            // [2048][256] fp32
    const unsigned short* __restrict__ wti,   // bf16 [256][256] n-major
    const float* __restrict__ bI,
    const float* __restrict__ projI,
    float* __restrict__ a2p, float* __restrict__ a2q)
{
  __shared__ __align__(16) unsigned short wlds[128 * 256];
  const int tid = threadIdx.x, bid = blockIdx.x;
  const int half = bid >> 5, bc = bid & 31;
  float* a2h = half ? a2q : a2p;
  const int nbg = half * 128;
  for (int i = 0; i < 16; ++i) {
    int cid = i * 256 + tid;
    int n = cid >> 5, kc = cid & 31;
    *(int4*)&wlds[n * 256 + ((kc ^ (n & 15)) << 3)] =
        *(const int4*)&wti[(size_t)(nbg + n) * 256 + kc * 8];
  }
  __syncthreads();
  const int w = tid >> 6, l = tid & 63, q = l >> 4, ln = l & 15;
  const int row = bc * 64 + w * 16 + ln;
  s8v af[8];
  for (int kf = 0; kf < 8; ++kf)
    af[kf] = cvt8(&io2[(size_t)row * 256 + kf * 32 + q * 8]);
  float p0 = 0.f, p1 = 0.f, p2 = 0.f, p3 = 0.f;
  for (int nt = 0; nt < 8; ++nt) {
    const int nloc = nt * 16 + ln;
    f32x4 c = {0.f, 0.f, 0.f, 0.f};
    for (int kf = 0; kf < 8; ++kf) {
      s8v bf = *(const s8v*)&wlds[nloc * 256 + (((kf * 4 + q) ^ (nloc & 15)) << 3)];
      c = mfma16(af[kf], bf, c);
    }
    const int ncol = nbg + nloc;
    const float bb = bI[ncol], pp = projI[ncol];
    p0 += pp * ftanh(c[0] + bb);
    p1 += pp * ftanh(c[1] + bb);
    p2 += pp * ftanh(c[2] + bb);
    p3 += pp * ftanh(c[3] + bb);
  }
  for (int d = 1; d < 16; d <<= 1) {
    p0 += __shfl_xor(p0, d);
    p1 += __shfl_xor(p1, d);
    p2 += __shfl_xor(p2, d);
    p3 += __shfl_xor(p3, d);
  }
  if (ln == 0) {
    const int r0 = bc * 64 + w * 16 + q * 4;
    a2h[r0] = p0; a2h[r0 + 1] = p1; a2h[r0 + 2] = p2; a2h[r0 + 3] = p3;
  }
}

// ============================================================================
// K7: doc_vec = sum_s a2 * io2 ; out = doc @ W_final^T + b_final
// ============================================================================
__global__ __launch_bounds__(256) void k_final(
    const float* __restrict__ a2p, const float* __restrict__ a2q,
    const float* __restrict__ io2,
    const float* __restrict__ wf,    // [5][256]
    const float* __restrict__ bfi,   // [5]
    float* __restrict__ out)         // [64][5]
{
  const int b = blockIdx.x, tid = threadIdx.x;
  __shared__ float av[S_];
  __shared__ float dv[256];
  __shared__ float red[4];
  if (tid < S_) av[tid] = a2p[tid * 64 + b] + a2q[tid * 64 + b];
  __syncthreads();
  float acc = 0.f;
  for (int s = 0; s < S_; ++s) acc += av[s] * io2[((size_t)(s * 64 + b)) * 256 + tid];
  dv[tid] = acc;
  __syncthreads();
  for (int c = 0; c < C_; ++c) {
    float pv = wf[c * 256 + tid] * dv[tid];
    for (int d = 1; d < 64; d <<= 1) pv += __shfl_xor(pv, d);
    const int w = tid >> 6, l = tid & 63;
    if (l == 0) red[w] = pv;
    __syncthreads();
    if (tid == 0)
      out[b * C_ + c] = red[0] + red[1] + red[2] + red[3] + bfi[c];
    __syncthreads();
  }
}

// ============================================================================
extern "C" void kernel_launch(void* const* d_in, const int* in_sizes, int n_in,
                              void* d_out, int out_size, void* d_ws, size_t ws_size,
                              hipStream_t stream) {
  (void)in_sizes; (void)n_in; (void)out_size; (void)ws_size;
  const int*   tokens = (const int*)d_in[0];
  const float* emb    = (const float*)d_in[1];
  const float* wih_a  = (const float*)d_in[2];
  const float* whh_a  = (const float*)d_in[3];
  const float* bih_a  = (const float*)d_in[4];
  const float* bhh_a  = (const float*)d_in[5];
  const float* ww_a   = (const float*)d_in[6];
  const float* b_a    = (const float*)d_in[7];
  const float* proj_a = (const float*)d_in[8];
  const float* wih_i  = (const float*)d_in[9];
  const float* whh_i  = (const float*)d_in[10];
  const float* bih_i  = (const float*)d_in[11];
  const float* bhh_i  = (const float*)d_in[12];
  const float* ww_i   = (const float*)d_in[13];
  const float* b_i    = (const float*)d_in[14];
  const float* proj_i = (const float*)d_in[15];
  const float* w_fin  = (const float*)d_in[16];
  const float* b_fin  = (const float*)d_in[17];

  char* ws = (char*)d_ws;
  unsigned short* gtab = (unsigned short*)(ws + 0);          // 49,152,000
  unsigned short* wta  = (unsigned short*)(ws + 49152000);   //    131,072
  unsigned short* iout = (unsigned short*)(ws + 49283072);   // 67,108,864
  float* a1  = (float*)(ws + 116391936);                     //    524,288
  float* sv  = (float*)(ws + 117440512);                     //  2,097,152
  float* xgi = (float*)(ws + 119537664);                     //  6,291,456
  float* io2 = (float*)(ws + 125829120);                     //  2,097,152
  float* a2p = (float*)(ws + 127926272);                     //      8,192
  float* a2q = (float*)(ws + 127934464);                     //      8,192
  unsigned short* wti = (unsigned short*)(ws + 127942656);   //    131,072

  k_gtab<<<3008, 256, 0, stream>>>(emb, wih_a, bih_a, bhh_a, ww_a, ww_i,
                                   gtab, wta, wti);
  k_intra<<<256, 256, 0, stream>>>(tokens, gtab, whh_a, bhh_a, iout);
  k_attn1<<<512, 256, 0, stream>>>(iout, wta, b_a, proj_a, a1);
  k_attn2<<<2048, 256, 0, stream>>>(a1, iout, sv);
  k_xgi<<<192, 256, 0, stream>>>(sv, wih_i, bih_i, bhh_i, xgi);
  k_inter<<<8, 256, 0, stream>>>(xgi, whh_i, bhh_i, io2);
  k_attn_i<<<64, 256, 0, stream>>>(io2, wti, b_i, proj_i, a2p, a2q);
  k_final<<<64, 256, 0, stream>>>(a2p, a2q, io2, w_fin, b_fin, (float*)d_out);
}